// Round 1
// baseline (172.897 us; speedup 1.0000x reference)
//
#include <hip/hip_runtime.h>
#include <cstdio>

static constexpr int  MPIX  = 51529;   // 227*227
static constexpr int  NBATCH = 8;
static constexpr int  NTH   = 256;     // number of thresholds
static constexpr int  HD    = 257;     // histogram dim (ranks 0..256)

// ws layout in floats:
// [0,256) psa | [256,512) ia(int) | [512,768) psb | [768,1024) ib(int)
static constexpr long H_OFF   = 1024;
static constexpr long H_SZ    = (long)NBATCH * HD * HD;     // 528392
static constexpr long GA_OFF  = H_OFF + H_SZ;               // 529416
static constexpr long GA_SZ   = (long)NBATCH * NTH * HD;    // 526336
static constexpr long GB_OFF  = GA_OFF + GA_SZ;             // 1055752
static constexpr long CSP_OFF = GB_OFF + GA_SZ;             // 1582088
static constexpr long CSP_SZ  = (long)NBATCH * NTH * NTH;   // 524288
static constexpr long OACC_OFF = CSP_OFF + CSP_SZ;          // 2106376
static constexpr long TOTAL_FLOATS = OACC_OFF + 256;        // 2106632  (~8.43 MB)

__global__ void k_zero(float4* __restrict__ p, long n4) {
    long i = (long)blockIdx.x * blockDim.x + threadIdx.x;
    long stride = (long)gridDim.x * blockDim.x;
    float4 z = make_float4(0.f, 0.f, 0.f, 0.f);
    for (; i < n4; i += stride) p[i] = z;
}

// rank-sort 256 values (stable on ties) -> sorted values + original indices
__global__ void k_sort(const float* __restrict__ pa, const float* __restrict__ pb,
                       float* __restrict__ psa, int* __restrict__ ia,
                       float* __restrict__ psb, int* __restrict__ ib) {
    int t = threadIdx.x;
    {
        float v = pa[t]; int c = 0;
        for (int j = 0; j < 256; ++j) { float w = pa[j]; c += (w < v) || (w == v && j < t); }
        psa[c] = v; ia[c] = t;
    }
    {
        float v = pb[t]; int c = 0;
        for (int j = 0; j < 256; ++j) { float w = pb[j]; c += (w < v) || (w == v && j < t); }
        psb[c] = v; ib[c] = t;
    }
}

__device__ __forceinline__ int d_ub(const float* arr, float v) { // first idx with arr[i] > v
    int lo = 0, hi = 256;
    while (lo < hi) { int m = (lo + hi) >> 1; if (arr[m] <= v) lo = m + 1; else hi = m; }
    return lo;
}
__device__ __forceinline__ int d_lb(const float* arr, float v) { // first idx with arr[i] >= v
    int lo = 0, hi = 256;
    while (lo < hi) { int m = (lo + hi) >> 1; if (arr[m] < v) lo = m + 1; else hi = m; }
    return lo;
}

// per-pixel scatter: histogram of rank pairs + fractional cross histograms + sparse f*g
__global__ void k_scatter(const float* __restrict__ x,
                          const float* __restrict__ psa, const float* __restrict__ psb,
                          float* __restrict__ H, float* __restrict__ Ga,
                          float* __restrict__ Gb, float* __restrict__ Csp) {
    __shared__ float la[256], lbv[256];
    int t = threadIdx.x;
    la[t]  = psa[t];
    lbv[t] = psb[t];
    __syncthreads();
    int b = blockIdx.y;
    int k = blockIdx.x * 256 + t;
    if (k >= MPIX) return;
    const float* xa = x + (long)b * MPIX;
    float a  = xa[k];
    float bd = a - ((k + 1 < MPIX) ? xa[k + 1] : 0.0f);

    int ca1 = d_ub(la,  a  - 1.0f);  // # thresholds fully saturated (value exactly 1)
    int ca0 = d_lb(la,  a);          // first threshold with value 0
    int cb1 = d_ub(lbv, bd - 1.0f);
    int cb0 = d_lb(lbv, bd);

    atomicAdd(&H[(long)b * HD * HD + (long)ca1 * HD + cb1], 1.0f);
    for (int r = ca1; r < ca0; ++r) {
        float f = fminf(fmaxf(a - la[r], 0.f), 1.f);
        atomicAdd(&Gb[((long)b * NTH + r) * HD + cb1], f);
    }
    for (int s = cb1; s < cb0; ++s) {
        float g = fminf(fmaxf(bd - lbv[s], 0.f), 1.f);
        atomicAdd(&Ga[((long)b * NTH + s) * HD + ca1], g);
    }
    for (int r = ca1; r < ca0; ++r) {
        float f = fminf(fmaxf(a - la[r], 0.f), 1.f);
        for (int s = cb1; s < cb0; ++s) {
            float g = fminf(fmaxf(bd - lbv[s], 0.f), 1.f);
            atomicAdd(&Csp[(long)b * NTH * NTH + (long)r * NTH + s], f * g);
        }
    }
}

// in-place suffix scan of a length-257 strided row (Hillis-Steele in LDS)
__global__ void k_scan257(float* __restrict__ base0, int rows_per_batch,
                          long batch_pitch, long row_pitch, long es) {
    __shared__ float s0[257], s1[257];
    int rho = blockIdx.x;
    float* base = base0 + (long)(rho / rows_per_batch) * batch_pitch
                        + (long)(rho % rows_per_batch) * row_pitch;
    int t = threadIdx.x;
    for (int i = t; i < 257; i += 256) s0[i] = base[(long)i * es];
    __syncthreads();
    float* src = s0; float* dst = s1;
    for (int d = 1; d < 257; d <<= 1) {
        for (int i = t; i < 257; i += 256)
            dst[i] = src[i] + ((i + d < 257) ? src[i + d] : 0.0f);
        __syncthreads();
        float* tmp = src; src = dst; dst = tmp;
    }
    for (int i = t; i < 257; i += 256) base[(long)i * es] = src[i];
}

// glcm_sorted[r][s] = SufH[r+1][s+1] + SufGa[s][r+1] + SufGb[r][s+1] + sparse (in-place in Csp)
__global__ void k_assemble(float* __restrict__ Csp, const float* __restrict__ H,
                           const float* __restrict__ Ga, const float* __restrict__ Gb) {
    int b = blockIdx.y, r = blockIdx.x, s = threadIdx.x;
    float v = H[(long)b * HD * HD + (long)(r + 1) * HD + (s + 1)]
            + Ga[((long)b * NTH + s) * HD + (r + 1)]
            + Gb[((long)b * NTH + r) * HD + (s + 1)];
    Csp[(long)b * NTH * NTH + (long)r * NTH + s] += v;
}

// out_acc[b][o] += sum over a 128-wide (r,s)-chunk of glcm[b][r][s] * W[ia[r]*256+ib[s]][o]
__global__ void k_matvec(const float* __restrict__ glcm, const float* __restrict__ W,
                         const int* __restrict__ ia, const int* __restrict__ ib,
                         float* __restrict__ oacc) {
    __shared__ float Wl[128][32];
    __shared__ float gl[8][128];
    int t  = threadIdx.x;
    int c  = blockIdx.x;        // 0..511
    int r  = c >> 1;
    int s0 = (c & 1) * 128;
    int ia_r = ia[r];

    // stage 128 gathered W rows (2 threads per row, 128B each)
    int rr = t >> 1, half = t & 1;
    int wrow = ia_r * 256 + ib[s0 + rr];
    const float4* srcW = reinterpret_cast<const float4*>(W + (long)wrow * 32 + half * 16);
    float4* dstW = reinterpret_cast<float4*>(&Wl[rr][half * 16]);
#pragma unroll
    for (int u = 0; u < 4; ++u) dstW[u] = srcW[u];

    // stage glcm chunk for all 8 batches
    int bb = t >> 5, j4 = (t & 31) * 4;
    *reinterpret_cast<float4*>(&gl[bb][j4]) =
        *reinterpret_cast<const float4*>(glcm + (long)bb * NTH * NTH + (long)r * NTH + s0 + j4);
    __syncthreads();

    int o = t & 31;
    float acc = 0.f;
#pragma unroll 8
    for (int kk = 0; kk < 128; ++kk) acc += gl[bb][kk] * Wl[kk][o];
    atomicAdd(&oacc[bb * 32 + o], acc);
}

__global__ void k_finalize(const float* __restrict__ oacc, const float* __restrict__ bias,
                           float* __restrict__ out) {
    int t = threadIdx.x;
    out[t] = fmaxf(oacc[t] + bias[t & 31], 0.0f);
}

extern "C" void kernel_launch(void* const* d_in, const int* in_sizes, int n_in,
                              void* d_out, int out_size, void* d_ws, size_t ws_size,
                              hipStream_t stream) {
    const float* x    = (const float*)d_in[0];
    const float* pa   = (const float*)d_in[1];
    const float* pb   = (const float*)d_in[2];
    const float* W    = (const float*)d_in[3];
    const float* bias = (const float*)d_in[4];
    float* out = (float*)d_out;
    float* ws  = (float*)d_ws;

    if (ws_size < (size_t)TOTAL_FLOATS * sizeof(float)) {
        fprintf(stderr, "kernel_launch: ws too small: %zu < %zu bytes\n",
                ws_size, (size_t)TOTAL_FLOATS * sizeof(float));
        return;
    }

    float* psa = ws;
    int*   ia  = (int*)(ws + 256);
    float* psb = ws + 512;
    int*   ib  = (int*)(ws + 768);
    float* H   = ws + H_OFF;
    float* Ga  = ws + GA_OFF;
    float* Gb  = ws + GB_OFF;
    float* Csp = ws + CSP_OFF;
    float* oacc = ws + OACC_OFF;

    long nz4 = (TOTAL_FLOATS - H_OFF) / 4;
    k_zero<<<dim3(512), dim3(256), 0, stream>>>((float4*)(ws + H_OFF), nz4);
    k_sort<<<dim3(1), dim3(256), 0, stream>>>(pa, pb, psa, ia, psb, ib);
    k_scatter<<<dim3((MPIX + 255) / 256, NBATCH), dim3(256), 0, stream>>>(x, psa, psb, H, Ga, Gb, Csp);
    // 2D suffix-sum of H: along q then along p
    k_scan257<<<dim3(NBATCH * HD), dim3(256), 0, stream>>>(H, HD, (long)HD * HD, (long)HD, (long)1);
    k_scan257<<<dim3(NBATCH * HD), dim3(256), 0, stream>>>(H, HD, (long)HD * HD, (long)1, (long)HD);
    // 1D suffix-sums of Ga (over ra) and Gb (over rb)
    k_scan257<<<dim3(NBATCH * NTH), dim3(256), 0, stream>>>(Ga, NTH, (long)NTH * HD, (long)HD, (long)1);
    k_scan257<<<dim3(NBATCH * NTH), dim3(256), 0, stream>>>(Gb, NTH, (long)NTH * HD, (long)HD, (long)1);
    k_assemble<<<dim3(NTH, NBATCH), dim3(256), 0, stream>>>(Csp, H, Ga, Gb);
    k_matvec<<<dim3(512), dim3(256), 0, stream>>>(Csp, W, ia, ib, oacc);
    k_finalize<<<dim3(1), dim3(256), 0, stream>>>(oacc, bias, out);
}

// Round 3
// 114.502 us; speedup vs baseline: 1.5100x; 1.5100x over previous
//
#include <hip/hip_runtime.h>
#include <cstdio>
#include <cstdint>

static constexpr int  MPIX   = 51529;   // 227*227
static constexpr int  NBATCH = 8;
static constexpr int  NTH    = 256;     // number of thresholds
static constexpr int  HD     = 257;     // rank histogram dim (0..256)

// ws layout (float slots)
static constexpr long PSA_OFF  = 0;     // 256 floats
static constexpr long IA_OFF   = 256;   // 256 ints
static constexpr long PSB_OFF  = 512;   // 256 floats
static constexpr long IB_OFF   = 768;   // 256 ints
static constexpr long KEYS_OFF = 1024;                              // u32 per pixel
static constexpr long KEYS_SZ  = (long)NBATCH * MPIX;               // 412232
static constexpr long H_OFF    = KEYS_OFF + KEYS_SZ;                // 413256
static constexpr long H_SZ     = (long)NBATCH * HD * HD;            // 528392
static constexpr long GAT_OFF  = H_OFF + H_SZ;                      // 941648
static constexpr long GAT_SZ   = (long)NBATCH * HD * NTH;           // 526336
static constexpr long GBC_OFF  = GAT_OFF + GAT_SZ;                  // 1467984
static constexpr long GBC_SZ   = (long)NBATCH * NTH * NTH;          // 524288
static constexpr long PART_OFF = GBC_OFF + GBC_SZ;                  // 1992272
static constexpr long PART_SZ  = 128 * 256;                         // 32768
static constexpr long TOTAL_FLOATS = PART_OFF + PART_SZ;            // 2025040 (~8.10 MB)

__device__ __forceinline__ float clamp01(float v) {
    return fminf(fmaxf(v, 0.f), 1.f);
}

// rank-sort 256 values (stable on ties) -> sorted values + original indices
__global__ void k_sort(const float* __restrict__ pa, const float* __restrict__ pb,
                       float* __restrict__ psa, int* __restrict__ ia,
                       float* __restrict__ psb, int* __restrict__ ib) {
    int t = threadIdx.x;
    {
        float v = pa[t]; int c = 0;
        for (int j = 0; j < 256; ++j) { float w = pa[j]; c += (w < v) || (w == v && j < t); }
        psa[c] = v; ia[c] = t;
    }
    {
        float v = pb[t]; int c = 0;
        for (int j = 0; j < 256; ++j) { float w = pb[j]; c += (w < v) || (w == v && j < t); }
        psb[c] = v; ib[c] = t;
    }
}

__device__ __forceinline__ int d_lb(const float* arr, float v) { // first idx with arr[i] >= v
    int lo = 0, hi = 256;
    while (lo < hi) { int m = (lo + hi) >> 1; if (arr[m] < v) lo = m + 1; else hi = m; }
    return lo;
}

// per-pixel rank keys: ca1(9) | cb1(9) | wa(7) | wb(7)
__global__ void k_keys(const float* __restrict__ x, const float* __restrict__ psa,
                       const float* __restrict__ psb, uint32_t* __restrict__ keys) {
    __shared__ float la[256], lb[256];
    int t = threadIdx.x;
    la[t] = psa[t];
    lb[t] = psb[t];
    __syncthreads();
    int b = blockIdx.y;
    int k = blockIdx.x * 256 + t;
    if (k >= MPIX) return;
    const float* xa = x + (long)b * MPIX;
    float a  = xa[k];
    float bd = a - ((k + 1 < MPIX) ? xa[k + 1] : 0.0f);

    int ca0 = d_lb(la, a);                 // first threshold with sa == 0
    int i = ca0; while (i > 0 && la[i - 1] > a - 1.0f) --i;
    int ca1 = i;                           // # thresholds fully saturated
    int cb0 = d_lb(lb, bd);
    i = cb0; while (i > 0 && lb[i - 1] > bd - 1.0f) --i;
    int cb1 = i;
    int wa = min(ca0 - ca1, 127);
    int wb = min(cb0 - cb1, 127);
    keys[(long)b * MPIX + k] = (uint32_t)ca1 | ((uint32_t)cb1 << 9)
                             | ((uint32_t)wa << 18) | ((uint32_t)wb << 25);
}

// Each block owns batch b and rank range [r0, r0+rlen) (rlen<=8).
// Accumulates H / Ga / Gb / Csp for its range in LDS (LDS atomics only),
// suffix-scans Gb and H rows along cb1 in LDS, flushes dense exclusive rows:
//   H[b][ca1][*]   (cb1-suffix-scanned)
//   GaT[b][ca1][s] (unscanned; ca1-scan later in k_scanB)
//   GbC[b][r][s] = SufGb[r][s+1] + Csp[r][s]   (fully finished)
__global__ void k_phase2(const float* __restrict__ x, const uint32_t* __restrict__ keys,
                         const float* __restrict__ psa, const float* __restrict__ psb,
                         float* __restrict__ H, float* __restrict__ GaT,
                         float* __restrict__ GbC) {
    __shared__ float la[256], lb[256];
    __shared__ float lH[8][257];
    __shared__ float lGb[8][257];
    __shared__ float lT[8][257];
    __shared__ float lGa[256][9];   // [s][ca1-r0], padded stride 9
    __shared__ float lCsp[8][256];

    int tid = threadIdx.x;            // block = 1024
    int b   = blockIdx.y;
    int r0  = blockIdx.x * 8;
    int rlen = min(8, HD - r0);       // group 32 -> 1

    // init
    for (int i = tid; i < 256; i += 1024) { la[i] = psa[i]; lb[i] = psb[i]; }
    for (int i = tid; i < 8 * 257; i += 1024) { (&lH[0][0])[i] = 0.f; (&lGb[0][0])[i] = 0.f; }
    for (int i = tid; i < 256 * 9; i += 1024) (&lGa[0][0])[i] = 0.f;
    for (int i = tid; i < 8 * 256; i += 1024) (&lCsp[0][0])[i] = 0.f;
    __syncthreads();

    const long kb = (long)b * MPIX;
    for (int k = tid; k < MPIX; k += 1024) {
        uint32_t key = keys[kb + k];
        int ca1 = key & 511;
        int wa  = (key >> 18) & 127;
        int d   = ca1 - r0;
        bool owna = (unsigned)d < (unsigned)rlen;
        int rlo = max(ca1, r0);
        int rhi = min(ca1 + wa, r0 + rlen);
        bool anyw = rlo < rhi;
        if (!owna && !anyw) continue;

        int cb1 = (key >> 9) & 511;
        int wb  = key >> 25;
        bool anyg = (wb > 0) && (owna || anyw);
        float a = 0.f, bd = 0.f;
        if (anyw || anyg) a = x[kb + k];
        if (anyg) bd = a - ((k + 1 < MPIX) ? x[kb + k + 1] : 0.f);

        if (owna) {
            atomicAdd(&lH[d][cb1], 1.0f);
            if (wb > 0)
                for (int s = cb1; s < cb1 + wb; ++s)
                    atomicAdd(&lGa[s][d], clamp01(bd - lb[s]));
        }
        for (int r = rlo; r < rhi; ++r) {
            float f = clamp01(a - la[r]);
            int rr = r - r0;
            atomicAdd(&lGb[rr][cb1], f);
            for (int s = cb1; s < cb1 + wb; ++s)
                atomicAdd(&lCsp[rr][s], f * clamp01(bd - lb[s]));
        }
    }
    __syncthreads();

    // suffix-scan lGb rows along cb1 (Hillis-Steele, ping-pong with lT)
    float* src = &lGb[0][0];
    float* dst = &lT[0][0];
    for (int dd = 1; dd < 257; dd <<= 1) {
        for (int i = tid; i < 8 * 257; i += 1024) {
            int c = i % 257;
            dst[i] = src[i] + ((c + dd < 257) ? src[i + dd] : 0.f);
        }
        __syncthreads();
        float* tmp = src; src = dst; dst = tmp;
    }
    // flush GbC (merge Csp) and GaT
    int rgb = max(0, min(rlen, NTH - r0));   // rows valid for Gb/Csp (r<256)
    for (int rr = 0; rr < rgb; ++rr) {
        float* gbS = src + rr * 257;
        float* dstg = GbC + ((long)b * NTH + (r0 + rr)) * NTH;
        for (int s = tid; s < 256; s += 1024) dstg[s] = gbS[s + 1] + lCsp[rr][s];
    }
    for (int c = 0; c < rlen; ++c) {
        float* dstg = GaT + ((long)b * HD + (r0 + c)) * NTH;
        for (int s = tid; s < 256; s += 1024) dstg[s] = lGa[s][c];
    }
    __syncthreads();

    // suffix-scan lH rows along cb1 (reuse lT)
    src = &lH[0][0];
    dst = &lT[0][0];
    for (int dd = 1; dd < 257; dd <<= 1) {
        for (int i = tid; i < 8 * 257; i += 1024) {
            int c = i % 257;
            dst[i] = src[i] + ((c + dd < 257) ? src[i + dd] : 0.f);
        }
        __syncthreads();
        float* tmp = src; src = dst; dst = tmp;
    }
    for (int rr = 0; rr < rlen; ++rr) {
        float* hS = src + rr * 257;
        float* dsth = H + ((long)b * HD + (r0 + rr)) * HD;
        for (int i = tid; i < 257; i += 1024) dsth[i] = hS[i];
    }
}

// suffix scans along ca1: H columns (es=257) and GaT columns (es=256)
__global__ void k_scanB(float* __restrict__ H, float* __restrict__ GaT) {
    __shared__ float s0[257], s1[257];
    int bx = blockIdx.x;
    float* base; long es;
    if (bx < NBATCH * HD) {
        int b = bx / HD, col = bx % HD;
        base = H + (long)b * HD * HD + col; es = HD;
    } else {
        int idx = bx - NBATCH * HD;
        int b = idx >> 8, s = idx & 255;
        base = GaT + (long)b * HD * NTH + s; es = NTH;
    }
    int t = threadIdx.x;
    for (int i = t; i < 257; i += 256) s0[i] = base[(long)i * es];
    __syncthreads();
    float* src = s0; float* dst = s1;
    for (int d = 1; d < 257; d <<= 1) {
        for (int i = t; i < 257; i += 256)
            dst[i] = src[i] + ((i + d < 257) ? src[i + d] : 0.0f);
        __syncthreads();
        float* tmp = src; src = dst; dst = tmp;
    }
    for (int i = t; i < 257; i += 256) base[(long)i * es] = src[i];
}

// fused assemble + matvec: 128 blocks, block c handles r in [2c,2c+2), both s-halves.
// glcm[b][r][s] = H[b][r+1][s+1] + GaT[b][r+1][s] + GbC[b][r][s]
__global__ void k_matvec(const float* __restrict__ H, const float* __restrict__ GaT,
                         const float* __restrict__ GbC, const float* __restrict__ W,
                         const int* __restrict__ ia, const int* __restrict__ ib,
                         float* __restrict__ partial) {
    __shared__ float Wl[128][32];
    __shared__ float gl[8][128];
    int t  = threadIdx.x;
    int bb = t >> 5, o = t & 31;
    float acc = 0.f;
#pragma unroll
    for (int it = 0; it < 4; ++it) {
        int r  = blockIdx.x * 2 + (it >> 1);   // 0..255
        int s0 = (it & 1) * 128;
        __syncthreads();   // protect previous round's LDS reads
        // stage 128 gathered W rows (2 threads per row, 64B each)
        int rr = t >> 1, half = t & 1;
        int wrow = ia[r] * 256 + ib[s0 + rr];
        const float4* srcW = reinterpret_cast<const float4*>(W + (long)wrow * 32 + half * 16);
        float4* dstW = reinterpret_cast<float4*>(&Wl[rr][half * 16]);
#pragma unroll
        for (int u = 0; u < 4; ++u) dstW[u] = srcW[u];
        // stage glcm chunk (assembled on the fly) for all 8 batches
        {
            int bS = t >> 5, j4 = (t & 31) * 4;
            int sb = s0 + j4;
            const float4 ga = *reinterpret_cast<const float4*>(
                GaT + ((long)bS * HD + (r + 1)) * NTH + sb);
            const float4 gb = *reinterpret_cast<const float4*>(
                GbC + ((long)bS * NTH + r) * NTH + sb);
            const float* hp = H + ((long)bS * HD + (r + 1)) * HD + 1 + sb;
            float4 v;
            v.x = hp[0] + ga.x + gb.x;
            v.y = hp[1] + ga.y + gb.y;
            v.z = hp[2] + ga.z + gb.z;
            v.w = hp[3] + ga.w + gb.w;
            *reinterpret_cast<float4*>(&gl[bS][j4]) = v;
        }
        __syncthreads();
#pragma unroll 8
        for (int kk = 0; kk < 128; ++kk) acc += gl[bb][kk] * Wl[kk][o];
    }
    partial[(long)blockIdx.x * 256 + t] = acc;
}

__global__ void k_finalize(const float* __restrict__ partial, const float* __restrict__ bias,
                           float* __restrict__ out) {
    int gt = blockIdx.x * 64 + threadIdx.x;   // grid 4 x 64 = 256 outputs
    float s = 0.f;
    for (int c = 0; c < 128; ++c) s += partial[(long)c * 256 + gt];
    out[gt] = fmaxf(s + bias[gt & 31], 0.0f);
}

extern "C" void kernel_launch(void* const* d_in, const int* in_sizes, int n_in,
                              void* d_out, int out_size, void* d_ws, size_t ws_size,
                              hipStream_t stream) {
    const float* x    = (const float*)d_in[0];
    const float* pa   = (const float*)d_in[1];
    const float* pb   = (const float*)d_in[2];
    const float* W    = (const float*)d_in[3];
    const float* bias = (const float*)d_in[4];
    float* out = (float*)d_out;
    float* ws  = (float*)d_ws;

    if (ws_size < (size_t)TOTAL_FLOATS * sizeof(float)) {
        fprintf(stderr, "kernel_launch: ws too small: %zu < %zu bytes\n",
                ws_size, (size_t)TOTAL_FLOATS * sizeof(float));
        return;
    }

    float*    psa  = ws + PSA_OFF;
    int*      ia   = (int*)(ws + IA_OFF);
    float*    psb  = ws + PSB_OFF;
    int*      ib   = (int*)(ws + IB_OFF);
    uint32_t* keys = (uint32_t*)(ws + KEYS_OFF);
    float*    H    = ws + H_OFF;
    float*    GaT  = ws + GAT_OFF;
    float*    GbC  = ws + GBC_OFF;
    float*    part = ws + PART_OFF;

    k_sort<<<dim3(1), dim3(256), 0, stream>>>(pa, pb, psa, ia, psb, ib);
    k_keys<<<dim3((MPIX + 255) / 256, NBATCH), dim3(256), 0, stream>>>(x, psa, psb, keys);
    k_phase2<<<dim3(33, NBATCH), dim3(1024), 0, stream>>>(x, keys, psa, psb, H, GaT, GbC);
    k_scanB<<<dim3(NBATCH * HD + NBATCH * NTH), dim3(256), 0, stream>>>(H, GaT);
    k_matvec<<<dim3(128), dim3(256), 0, stream>>>(H, GaT, GbC, W, ia, ib, part);
    k_finalize<<<dim3(4), dim3(64), 0, stream>>>(part, bias, out);
}

// Round 4
// 83.181 us; speedup vs baseline: 2.0786x; 1.3765x over previous
//
#include <hip/hip_runtime.h>
#include <cstdio>
#include <cstdint>

static constexpr int  MPIX   = 51529;   // 227*227
static constexpr int  NBATCH = 8;
static constexpr int  NTH    = 256;     // number of thresholds
static constexpr int  HD     = 257;     // rank histogram dim (0..256)
static constexpr int  GRP    = 33;      // ceil(257/8) rank groups of 8
static constexpr int  BINCAP = 3968;    // records per (batch,group) bin (~2.2x expected)

// ws layout (float slots)
static constexpr long PSA_OFF  = 0;     // 256 floats (sorted phi_a)
static constexpr long IA_OFF   = 256;   // 256 ints   (orig idx of sorted phi_a)
static constexpr long PSB_OFF  = 512;   // 256 floats
static constexpr long IB_OFF   = 768;   // 256 ints
static constexpr long CUR_OFF  = 1024;  // NBATCH*GRP=264 ints (bin cursors)
static constexpr long H_OFF    = 1536;
static constexpr long H_SZ     = (long)NBATCH * HD * HD;        // 528392
static constexpr long GBC_OFF  = H_OFF + H_SZ;                  // 529928
static constexpr long GBC_SZ   = (long)NBATCH * NTH * NTH;      // 524288
static constexpr long BINS_OFF = GBC_OFF + GBC_SZ;              // 1054216
static constexpr long BINS_SZ  = (long)NBATCH * GRP * BINCAP;   // 1047552
// partials overlap bins: bins are dead by the time k_matvec runs (in-stream order)
static constexpr long PART_OFF = BINS_OFF;                      // 128*256 = 32768 <= BINS_SZ
static constexpr long TOTAL_FLOATS = BINS_OFF + BINS_SZ;        // 2101768 (~8.41 MB <= proven 8.43)

__device__ __forceinline__ float clamp01(float v) {
    return fminf(fmaxf(v, 0.f), 1.f);
}

// first idx with arr[i] >= v (arr ascending, length 256, in LDS)
__device__ __forceinline__ int d_lb(const float* arr, float v) {
    int lo = 0, hi = 256;
    while (lo < hi) { int m = (lo + hi) >> 1; if (arr[m] < v) lo = m + 1; else hi = m; }
    return lo;
}

// a-side decode: ca1 = #fully-saturated thresholds, wa = #fractional thresholds (capped 127)
__device__ __forceinline__ void decodeA(const float* la, float a, int& ca1, int& wa) {
    int ca0 = d_lb(la, a);
    int i = ca0;
    while (i > 0 && la[i - 1] > a - 1.0f) --i;
    ca1 = i;
    wa = min(ca0 - ca1, 127);
}

// rank-sort 256 values (stable) -> sorted values + original indices; also zero bin cursors
__global__ void k_sort(const float* __restrict__ pa, const float* __restrict__ pb,
                       float* __restrict__ psa, int* __restrict__ ia,
                       float* __restrict__ psb, int* __restrict__ ib,
                       int* __restrict__ cursor) {
    __shared__ float sa[256], sb[256];
    int t = threadIdx.x;
    sa[t] = pa[t];
    sb[t] = pb[t];
    for (int i = t; i < NBATCH * GRP; i += 256) cursor[i] = 0;
    __syncthreads();
    {
        float v = sa[t]; int c = 0;
        for (int j = 0; j < 256; ++j) { float w = sa[j]; c += (w < v) || (w == v && j < t); }
        psa[c] = v; ia[c] = t;
    }
    {
        float v = sb[t]; int c = 0;
        for (int j = 0; j < 256; ++j) { float w = sb[j]; c += (w < v) || (w == v && j < t); }
        psb[c] = v; ib[c] = t;
    }
}

// scatter pixel indices into per-(batch, rank-group) bins.
// pixel touches groups [ca1>>3 .. (ca1+max(wa,1)-1)>>3]
__global__ void k_bin(const float* __restrict__ x, const float* __restrict__ psa,
                      int* __restrict__ cursor, int* __restrict__ bins) {
    __shared__ float la[256];
    __shared__ int lcnt[GRP], lbase[GRP];
    int tid = threadIdx.x;            // block = 1024
    if (tid < 256) la[tid] = psa[tid];
    if (tid < GRP) lcnt[tid] = 0;
    __syncthreads();
    int b = blockIdx.y;
    int k = blockIdx.x * 1024 + tid;
    bool valid = k < MPIX;
    int g0 = 0, g1 = -1;
    if (valid) {
        float a = x[(long)b * MPIX + k];
        int ca1, wa;
        decodeA(la, a, ca1, wa);
        g0 = ca1 >> 3;
        g1 = (ca1 + max(wa, 1) - 1) >> 3;
        for (int g = g0; g <= g1; ++g) atomicAdd(&lcnt[g], 1);
    }
    __syncthreads();
    if (tid < GRP) {
        lbase[tid] = atomicAdd(&cursor[b * GRP + tid], lcnt[tid]);
        lcnt[tid] = 0;
    }
    __syncthreads();
    if (valid) {
        for (int g = g0; g <= g1; ++g) {
            int r = atomicAdd(&lcnt[g], 1);
            int slot = lbase[g] + r;
            if (slot < BINCAP) bins[((long)b * GRP + g) * BINCAP + slot] = k;
        }
    }
}

// Each block owns batch b and rank range [r0, r0+rlen) (rlen<=8); reads only its bin.
// Accumulates lH / lGa / lGb / lCsp in LDS, suffix-scans rows along cb1, flushes:
//   H[b][p][q] = rowScanH[p][q] + lGa[q-1][p-r0]   (ca1-scan later finishes both terms)
//   GbC[b][r][s] = SufGb[r][s+1] + Csp[r][s]        (fully finished)
__global__ void k_phase2(const float* __restrict__ x, const int* __restrict__ bins,
                         const int* __restrict__ cursor,
                         const float* __restrict__ psa, const float* __restrict__ psb,
                         float* __restrict__ H, float* __restrict__ GbC) {
    __shared__ float la[256], lb[256];
    __shared__ float lH[8][257];
    __shared__ float lGb[8][257];
    __shared__ float lT[8][257];
    __shared__ float lGa[256][9];   // [s][ca1-r0], padded stride 9
    __shared__ float lCsp[8][256];

    int tid = threadIdx.x;            // block = 1024
    int b   = blockIdx.y;
    int g   = blockIdx.x;
    int r0  = g * 8;
    int rlen = min(8, HD - r0);

    for (int i = tid; i < 256; i += 1024) { la[i] = psa[i]; lb[i] = psb[i]; }
    for (int i = tid; i < 8 * 257; i += 1024) { (&lH[0][0])[i] = 0.f; (&lGb[0][0])[i] = 0.f; }
    for (int i = tid; i < 256 * 9; i += 1024) (&lGa[0][0])[i] = 0.f;
    for (int i = tid; i < 8 * 256; i += 1024) (&lCsp[0][0])[i] = 0.f;
    __syncthreads();

    const long kb = (long)b * MPIX;
    int cnt = min(cursor[b * GRP + g], BINCAP);
    const int* mybin = bins + ((long)b * GRP + g) * BINCAP;

    for (int i = tid; i < cnt; i += 1024) {
        int k = mybin[i];
        float a  = x[kb + k];
        float bd = a - ((k + 1 < MPIX) ? x[kb + k + 1] : 0.f);
        int ca1, wa, cb1, wb;
        decodeA(la, a, ca1, wa);
        {
            int cb0 = d_lb(lb, bd);
            int j = cb0;
            while (j > 0 && lb[j - 1] > bd - 1.0f) --j;
            cb1 = j;
            wb = min(cb0 - cb1, 127);
        }
        int d = ca1 - r0;
        bool owna = (unsigned)d < (unsigned)rlen;
        int rlo = max(ca1, r0);
        int rhi = min(ca1 + wa, r0 + rlen);

        if (owna) {
            atomicAdd(&lH[d][cb1], 1.0f);
            for (int s = cb1; s < cb1 + wb; ++s)
                atomicAdd(&lGa[s][d], clamp01(bd - lb[s]));
        }
        for (int r = rlo; r < rhi; ++r) {
            float f = clamp01(a - la[r]);
            int rr = r - r0;
            atomicAdd(&lGb[rr][cb1], f);
            for (int s = cb1; s < cb1 + wb; ++s)
                atomicAdd(&lCsp[rr][s], f * clamp01(bd - lb[s]));
        }
    }
    __syncthreads();

    // suffix-scan lGb rows along cb1 (Hillis-Steele, ping-pong with lT)
    float* src = &lGb[0][0];
    float* dst = &lT[0][0];
    for (int dd = 1; dd < 257; dd <<= 1) {
        for (int i = tid; i < 8 * 257; i += 1024) {
            int c = i % 257;
            dst[i] = src[i] + ((c + dd < 257) ? src[i + dd] : 0.f);
        }
        __syncthreads();
        float* tmp = src; src = dst; dst = tmp;
    }
    // flush GbC (merge Csp)
    int rgb = max(0, min(rlen, NTH - r0));   // rows valid for Gb/Csp (r<256)
    for (int rr = 0; rr < rgb; ++rr) {
        float* gbS = src + rr * 257;
        float* dstg = GbC + ((long)b * NTH + (r0 + rr)) * NTH;
        for (int s = tid; s < 256; s += 1024) dstg[s] = gbS[s + 1] + lCsp[rr][s];
    }
    __syncthreads();

    // suffix-scan lH rows along cb1 (reuse lT)
    src = &lH[0][0];
    dst = &lT[0][0];
    for (int dd = 1; dd < 257; dd <<= 1) {
        for (int i = tid; i < 8 * 257; i += 1024) {
            int c = i % 257;
            dst[i] = src[i] + ((c + dd < 257) ? src[i + dd] : 0.f);
        }
        __syncthreads();
        float* tmp = src; src = dst; dst = tmp;
    }
    // flush H rows with Ga merged: H[p][q] = rowScanH[p][q] + lGa[q-1][p-r0]
    for (int rr = 0; rr < rlen; ++rr) {
        float* hS = src + rr * 257;
        float* dsth = H + ((long)b * HD + (r0 + rr)) * HD;
        for (int q = tid; q < 257; q += 1024)
            dsth[q] = hS[q] + ((q >= 1) ? lGa[q - 1][rr] : 0.f);
    }
}

// suffix scans along ca1 (H columns, stride HD)
__global__ void k_scanB(float* __restrict__ H) {
    __shared__ float s0[257], s1[257];
    int b = blockIdx.x / HD, col = blockIdx.x % HD;
    float* base = H + (long)b * HD * HD + col;
    int t = threadIdx.x;
    for (int i = t; i < 257; i += 256) s0[i] = base[(long)i * HD];
    __syncthreads();
    float* src = s0; float* dst = s1;
    for (int d = 1; d < 257; d <<= 1) {
        for (int i = t; i < 257; i += 256)
            dst[i] = src[i] + ((i + d < 257) ? src[i + d] : 0.0f);
        __syncthreads();
        float* tmp = src; src = dst; dst = tmp;
    }
    for (int i = t; i < 257; i += 256) base[(long)i * HD] = src[i];
}

// fused assemble + matvec: 128 blocks, block c handles r in [2c,2c+2), both s-halves.
// glcm[b][r][s] = H[b][r+1][s+1] + GbC[b][r][s]   (H already includes Ga term)
__global__ void k_matvec(const float* __restrict__ H, const float* __restrict__ GbC,
                         const float* __restrict__ W,
                         const int* __restrict__ ia, const int* __restrict__ ib,
                         float* __restrict__ partial) {
    __shared__ float Wl[128][32];
    __shared__ float gl[8][128];
    int t  = threadIdx.x;
    int bb = t >> 5, o = t & 31;
    float acc = 0.f;
#pragma unroll
    for (int it = 0; it < 4; ++it) {
        int r  = blockIdx.x * 2 + (it >> 1);   // 0..255
        int s0 = (it & 1) * 128;
        __syncthreads();   // protect previous round's LDS reads
        // stage 128 gathered W rows (2 threads per row, 64B each)
        int rr = t >> 1, half = t & 1;
        int wrow = ia[r] * 256 + ib[s0 + rr];
        const float4* srcW = reinterpret_cast<const float4*>(W + (long)wrow * 32 + half * 16);
        float4* dstW = reinterpret_cast<float4*>(&Wl[rr][half * 16]);
#pragma unroll
        for (int u = 0; u < 4; ++u) dstW[u] = srcW[u];
        // stage glcm chunk (assembled on the fly) for all 8 batches
        {
            int bS = t >> 5, j4 = (t & 31) * 4;
            int sb = s0 + j4;
            const float4 gb = *reinterpret_cast<const float4*>(
                GbC + ((long)bS * NTH + r) * NTH + sb);
            const float* hp = H + ((long)bS * HD + (r + 1)) * HD + 1 + sb;
            float4 v;
            v.x = hp[0] + gb.x;
            v.y = hp[1] + gb.y;
            v.z = hp[2] + gb.z;
            v.w = hp[3] + gb.w;
            *reinterpret_cast<float4*>(&gl[bS][j4]) = v;
        }
        __syncthreads();
#pragma unroll 8
        for (int kk = 0; kk < 128; ++kk) acc += gl[bb][kk] * Wl[kk][o];
    }
    partial[(long)blockIdx.x * 256 + t] = acc;
}

__global__ void k_finalize(const float* __restrict__ partial, const float* __restrict__ bias,
                           float* __restrict__ out) {
    int gt = blockIdx.x * 64 + threadIdx.x;   // grid 4 x 64 = 256 outputs
    float s = 0.f;
    for (int c = 0; c < 128; ++c) s += partial[(long)c * 256 + gt];
    out[gt] = fmaxf(s + bias[gt & 31], 0.0f);
}

extern "C" void kernel_launch(void* const* d_in, const int* in_sizes, int n_in,
                              void* d_out, int out_size, void* d_ws, size_t ws_size,
                              hipStream_t stream) {
    const float* x    = (const float*)d_in[0];
    const float* pa   = (const float*)d_in[1];
    const float* pb   = (const float*)d_in[2];
    const float* W    = (const float*)d_in[3];
    const float* bias = (const float*)d_in[4];
    float* out = (float*)d_out;
    float* ws  = (float*)d_ws;

    if (ws_size < (size_t)TOTAL_FLOATS * sizeof(float)) {
        fprintf(stderr, "kernel_launch: ws too small: %zu < %zu bytes\n",
                ws_size, (size_t)TOTAL_FLOATS * sizeof(float));
        return;
    }

    float* psa    = ws + PSA_OFF;
    int*   ia     = (int*)(ws + IA_OFF);
    float* psb    = ws + PSB_OFF;
    int*   ib     = (int*)(ws + IB_OFF);
    int*   cursor = (int*)(ws + CUR_OFF);
    float* H      = ws + H_OFF;
    float* GbC    = ws + GBC_OFF;
    int*   bins   = (int*)(ws + BINS_OFF);
    float* part   = ws + PART_OFF;   // overlaps bins (bins dead by matvec)

    k_sort<<<dim3(1), dim3(256), 0, stream>>>(pa, pb, psa, ia, psb, ib, cursor);
    k_bin<<<dim3((MPIX + 1023) / 1024, NBATCH), dim3(1024), 0, stream>>>(x, psa, cursor, bins);
    k_phase2<<<dim3(GRP, NBATCH), dim3(1024), 0, stream>>>(x, bins, cursor, psa, psb, H, GbC);
    k_scanB<<<dim3(NBATCH * HD), dim3(256), 0, stream>>>(H);
    k_matvec<<<dim3(128), dim3(256), 0, stream>>>(H, GbC, W, ia, ib, part);
    k_finalize<<<dim3(4), dim3(64), 0, stream>>>(part, bias, out);
}